// Round 5
// baseline (617.085 us; speedup 1.0000x reference)
//
#include <hip/hip_runtime.h>

// Problem constants (from reference): B=64, TQ=1, TK=2048, QD=KD=512, U=1024, H=8, D=128
#define B_   64
#define TK_  2048
#define KD_  512
#define U_   1024
#define H_   8
#define D_   128
#define MT   64              // t-rows per workgroup tile
#define APAD 8               // pad 8 bf16 (16B) -> 2-way LDS bank conflicts only (free)
#define ASTR (KD_ + APAD)    // 520 shorts per row
#define NTILE (TK_ / MT)     // 32 t-tiles per batch
#define GRID (B_ * NTILE)    // 2048 workgroups

typedef float f32x4 __attribute__((ext_vector_type(4)));
typedef short short8 __attribute__((ext_vector_type(8)));

__device__ __forceinline__ short f2bf(float f) {
    unsigned u = __float_as_uint(f);
    u += 0x7fffu + ((u >> 16) & 1u);          // round-to-nearest-even
    return (short)(u >> 16);
}
__device__ __forceinline__ float bf2f(short s) {
    return __uint_as_float(((unsigned)(unsigned short)s) << 16);
}
__device__ __forceinline__ float tanh_fast(float x) {
    // tanh(x) = 1 - 2/(1+exp(2x)); exact at +-inf saturation, ~1e-6 rel err
    float e = __builtin_amdgcn_exp2f(x * 2.885390081777927f);   // exp(2x)
    return 1.0f - 2.0f * __builtin_amdgcn_rcpf(1.0f + e);
}

// ---------------- setup kernel 1: normed_v = g * v * rsqrt(sum v^2) ----------------
__global__ void nv_kernel(const float* __restrict__ v, float* __restrict__ wsNV) {
    __shared__ float red[D_];
    int tid = threadIdx.x;
    float x = v[tid];
    red[tid] = x * x;
    __syncthreads();
    if (tid == 0) {
        float s = 0.f;
        for (int i = 0; i < D_; ++i) s += red[i];
        red[0] = rsqrtf(s) * 0.08838834764831845f;   // 1/sqrt(128)
    }
    __syncthreads();
    wsNV[tid] = x * red[0];
}

// ---------------- setup kernel 2: qb[b][u] = query[b,:].Wq[u,:] + bq[u] + bk[u] ----------------
__global__ void q_kernel(const float* __restrict__ query, const float* __restrict__ Wq,
                         const float* __restrict__ bq, const float* __restrict__ bk,
                         float* __restrict__ wsQ) {
    __shared__ float qrow[KD_];
    int b = blockIdx.x, ug = blockIdx.y, tid = threadIdx.x;
    if (tid < 128) ((float4*)qrow)[tid] = ((const float4*)(query + (size_t)b * KD_))[tid];
    __syncthreads();
    int u = ug * 256 + tid;
    const float4* wq = (const float4*)(Wq + (size_t)u * KD_);
    const float4* q4 = (const float4*)qrow;
    float acc = 0.f;
#pragma unroll 8
    for (int i = 0; i < KD_ / 4; ++i) {
        float4 a = q4[i], w = wq[i];
        acc += a.x * w.x + a.y * w.y + a.z * w.z + a.w * w.w;
    }
    wsQ[(size_t)b * U_ + u] = acc + bq[u] + bk[u];
}

// ---------------- setup kernel 3: swizzle Wk (fp32) into fragment-major bf16 ----------------
// LANE-CONTIGUOUS layout: short8 index = ks*4096 + h*512 + l*8 + nf
//   (h = head = ublk>>3, nf = ublk&7). Each lane's 8 nf-frags are contiguous 128B ->
//   all 8 GSTEP loads fold into offset:0..112 off ONE 64-bit address; each wave's
//   per-ks footprint is one contiguous 8KB block (L2-friendly streaming).
// frag content unchanged: lane l, frag (h,nf): u = h*128 + nf*16 + (l&15),
//   k = ks*32 + (l>>4)*8 + j
__global__ void swz_kernel(const float* __restrict__ Wk, short* __restrict__ wsB) {
    int g = blockIdx.x * 256 + threadIdx.x;   // 0..65535 lane-frags
    int slot = g >> 6, l = g & 63;
    int ublk = slot >> 4, ks = slot & 15;
    int u = ublk * 16 + (l & 15);
    int k0 = ks * 32 + ((l >> 4) << 3);
    const float* src = Wk + (size_t)u * KD_ + k0;
    short8 o;
#pragma unroll
    for (int j = 0; j < 8; ++j) o[j] = f2bf(src[j]);
    int h = ublk >> 3, nf = ublk & 7;
    size_t oidx = (size_t)ks * 4096 + h * 512 + l * 8 + nf;
    *(short8*)(wsB + oidx * 8) = o;
}

// ---------------- main fused kernel ----------------
// grid: 2048 = 64 b * 32 t-tiles; block 256 (4 waves); 2 WGs/CU (LDS ~70.7 KB)
// 2-deep in-chunk B prefetch (bbA/bbB). Register discipline (anti-spill):
//  - qv/nv loaded INSIDE the epilogue (L2-hit reloads), not held across the GEMM
//  - only bbA (32 regs) crosses SCORE_EPI (carrying chunk-1 ks=0)
//  - lane-contiguous wsB: 8 frag loads = 1 vaddr + imm offsets (no per-load VALU)
// ATOMIC=false: write per-block partial ctx to `outp` (ws), reduced by reduce_kernel.
// ATOMIC=true : legacy fallback, atomicAdd into out (requires pre-zeroed out).

#define LOAD_A(a_, ksv)                                                               \
    _Pragma("unroll")                                                                 \
    for (int mf = 0; mf < 4; ++mf)                                                    \
        a_[mf] = *(const short8*)&As[(mf * 16 + l15) * ASTR + (ksv) * 32 + (lq << 3)];

#define MFMA32(a_, buf)                                                               \
    __builtin_amdgcn_s_setprio(1);                                                    \
    _Pragma("unroll")                                                                 \
    for (int mf = 0; mf < 4; ++mf)                                                    \
        _Pragma("unroll")                                                             \
        for (int nf = 0; nf < 8; ++nf)                                                \
            acc[mf][nf] = __builtin_amdgcn_mfma_f32_16x16x32_bf16(a_[mf], buf[nf],    \
                                                                  acc[mf][nf], 0, 0, 0); \
    __builtin_amdgcn_s_setprio(0);

#define PREF_B(buf, pidx)                                                             \
    _Pragma("unroll")                                                                 \
    for (int nf = 0; nf < 8; ++nf) buf[nf] = bp[(pidx) + nf];

#define GSTEP(ksv, buf, pidx) { short8 a_[4]; LOAD_A(a_, ksv); MFMA32(a_, buf); PREF_B(buf, pidx); }
#define GSTEP_NP(ksv, buf)    { short8 a_[4]; LOAD_A(a_, ksv); MFMA32(a_, buf); }

#define ZERO_ACC                                                                      \
    _Pragma("unroll")                                                                 \
    for (int mf = 0; mf < 4; ++mf)                                                    \
        _Pragma("unroll")                                                             \
        for (int nf = 0; nf < 8; ++nf) acc[mf][nf] = (f32x4){0.f, 0.f, 0.f, 0.f};

// score epilogue: s[t][h] = sum_d nv[d] * tanh(k + qb)
// qv/nv loaded here (L2-hit, reused 16x each) instead of being live across the GEMM.
// C/D layout: row t = mf*16 + lq*4 + r, col d = nf*16 + l15
#define SCORE_EPI(ubv, hh)                                                            \
    {                                                                                 \
        float qv_[8], nv_[8];                                                         \
        _Pragma("unroll")                                                             \
        for (int nf = 0; nf < 8; ++nf) {                                              \
            int d = nf * 16 + l15;                                                    \
            qv_[nf] = wsQ[(size_t)b * U_ + (ubv) + d];                                \
            nv_[nf] = wsNV[d];                                                        \
        }                                                                             \
        _Pragma("unroll")                                                             \
        for (int mf = 0; mf < 4; ++mf)                                                \
            _Pragma("unroll")                                                         \
            for (int r = 0; r < 4; ++r) {                                             \
                float p = 0.f;                                                        \
                _Pragma("unroll")                                                     \
                for (int nf = 0; nf < 8; ++nf)                                        \
                    p += nv_[nf] * tanh_fast(acc[mf][nf][r] + qv_[nf]);               \
                p += __shfl_xor(p, 1);                                                \
                p += __shfl_xor(p, 2);                                                \
                p += __shfl_xor(p, 4);                                                \
                p += __shfl_xor(p, 8);                                                \
                if (l15 == 0) S[mf * 16 + lq * 4 + r][hh] = p;                        \
            }                                                                         \
    }

template <bool ATOMIC>
__global__ __launch_bounds__(256, 2) void attn_kernel(
    const float* __restrict__ key, const short* __restrict__ wsB,
    const float* __restrict__ wsQ, const float* __restrict__ wsNV,
    float* __restrict__ outp)
{
    __shared__ short As[MT * ASTR];   // bf16 key tile, reused for GEMM-A and value
    __shared__ float S[MT][H_];       // scores
    __shared__ float Wt[MT][H_];      // softmax weights

    int bx = blockIdx.x;
    int b = bx & 63, tt = bx >> 6;
    int tid = threadIdx.x;
    int w = tid >> 6, l = tid & 63;
    int l15 = l & 15, lq = l >> 4;
    const short8* bp = (const short8*)wsB;

    // each (wave, chunk) covers exactly one head: chunk0 -> h=w, chunk1 -> h=4+w
    int ub0 = w * 128, ub1 = 512 + w * 128;
    // lane-contiguous wsB: base short8 index for (ks=0, head, lane)
    int bidx0 = w * 512 + l * 8;              // head w
    int bidx1 = (4 + w) * 512 + l * 8;        // head 4+w

    // ---- prefetch chunk-0 B-frags (ks=0,1) BEFORE the staging barrier ----
    // (global reads, no LDS dependency: latency hides under the stage phase)
    short8 bbA[8], bbB[8];
    PREF_B(bbA, bidx0);
    PREF_B(bbB, bidx0 + 4096);

    // ---- stage key tile [64 x 512] fp32 -> bf16 LDS (coalesced float4) ----
    const float4* src = (const float4*)(key + ((size_t)b * TK_ + (size_t)tt * MT) * KD_);
#pragma unroll 8
    for (int j = 0; j < 32; ++j) {
        int i = tid + j * 256;                 // 8192 float4 total
        float4 v = src[i];
        int t = i >> 7, c4 = (i & 127) << 2;
        short4 h4;
        h4.x = f2bf(v.x); h4.y = f2bf(v.y); h4.z = f2bf(v.z); h4.w = f2bf(v.w);
        *(short4*)&As[t * ASTR + c4] = h4;
    }
    __syncthreads();

    f32x4 acc[4][8];

    // ---- chunk 0 GEMM: 2-deep software-pipelined B prefetch ----
    ZERO_ACC;
#pragma unroll 1
    for (int ks = 0; ks < 14; ks += 2) {
        GSTEP(ks,     bbA, bidx0 + (ks + 2) * 4096);
        GSTEP(ks + 1, bbB, bidx0 + (ks + 3) * 4096);
    }
    // tail: after ks=14 consumes bbA, refill bbA with chunk-1 ks=0 (only 32 regs
    // cross the epilogue); bbB is consumed by ks=15 and left dead over the epilogue.
    GSTEP(14, bbA, bidx1);
    GSTEP_NP(15, bbB);
    SCORE_EPI(ub0, w);                         // bbA (chunk-1 ks0) in flight under this

    // ---- low-pressure window: chunk-1 ks=1 prefetch ----
    PREF_B(bbB, bidx1 + 4096);

    // ---- chunk 1 GEMM ----
    ZERO_ACC;
#pragma unroll 1
    for (int ks = 0; ks < 14; ks += 2) {
        GSTEP(ks,     bbA, bidx1 + (ks + 2) * 4096);
        GSTEP(ks + 1, bbB, bidx1 + (ks + 3) * 4096);
    }
    GSTEP_NP(14, bbA);
    GSTEP_NP(15, bbB);
    SCORE_EPI(ub1, 4 + w);
    __syncthreads();

    // ---- softmax over HEADS per t (legacy F.softmax dim=1) ----
    if (tid < MT) {
        f32x4 s0 = *(const f32x4*)&S[tid][0];
        f32x4 s1 = *(const f32x4*)&S[tid][4];
        float mx = fmaxf(fmaxf(fmaxf(s0[0], s0[1]), fmaxf(s0[2], s0[3])),
                         fmaxf(fmaxf(s1[0], s1[1]), fmaxf(s1[2], s1[3])));
        f32x4 e0, e1;
        float sum = 0.f;
#pragma unroll
        for (int h = 0; h < 4; ++h) {
            e0[h] = __builtin_amdgcn_exp2f((s0[h] - mx) * 1.4426950408889634f);
            sum += e0[h];
        }
#pragma unroll
        for (int h = 0; h < 4; ++h) {
            e1[h] = __builtin_amdgcn_exp2f((s1[h] - mx) * 1.4426950408889634f);
            sum += e1[h];
        }
        float inv = __builtin_amdgcn_rcpf(sum);
#pragma unroll
        for (int h = 0; h < 4; ++h) { e0[h] *= inv; e1[h] *= inv; }
        *(f32x4*)&Wt[tid][0] = e0;
        *(f32x4*)&Wt[tid][4] = e1;
    }
    __syncthreads();

    // ---- partial context: ctx[h][d] = sum_t w[t][h] * key[t][d] ----
    int dg = (tid & 127) << 2;        // d group of 4
    int hb = (tid >> 7) << 2;         // h base: 0 or 4
    float cacc[4][4] = {};
#pragma unroll 4
    for (int t = 0; t < MT; ++t) {
        short4 kk = *(const short4*)&As[t * ASTR + dg];
        f32x4 wt4 = *(const f32x4*)&Wt[t][hb];   // one b128 broadcast read
        float k0 = bf2f(kk.x), k1 = bf2f(kk.y), k2 = bf2f(kk.z), k3 = bf2f(kk.w);
#pragma unroll
        for (int j = 0; j < 4; ++j) {
            cacc[j][0] += wt4[j] * k0; cacc[j][1] += wt4[j] * k1;
            cacc[j][2] += wt4[j] * k2; cacc[j][3] += wt4[j] * k3;
        }
    }
    if (ATOMIC) {
        float* ob = outp + (size_t)b * (H_ * KD_);
#pragma unroll
        for (int j = 0; j < 4; ++j)
#pragma unroll
            for (int d = 0; d < 4; ++d)
                atomicAdd(&ob[(hb + j) * KD_ + dg + d], cacc[j][d]);
    } else {
        // fully coalesced float4 stores: block-private partial [8][512]
        float* pb = outp + (size_t)bx * (H_ * KD_);
#pragma unroll
        for (int j = 0; j < 4; ++j)
            *(f32x4*)&pb[(hb + j) * KD_ + dg] = *(f32x4*)&cacc[j][0];
    }
}

// ---------------- reduce kernel: out[b][u] = sum_tt partial[tt*64+b][u] ----------------
__global__ void reduce_kernel(const float* __restrict__ partial, float* __restrict__ out) {
    int o = blockIdx.x * 256 + threadIdx.x;   // float4 index, 65536 total
    int b = o >> 10;                          // 1024 float4 per batch
    int u4 = o & 1023;
    const f32x4* p4 = (const f32x4*)partial;
    f32x4 s = {0.f, 0.f, 0.f, 0.f};
#pragma unroll 8
    for (int tt = 0; tt < NTILE; ++tt)
        s += p4[((size_t)(tt * 64 + b)) * 1024 + u4];
    ((f32x4*)out)[o] = s;
}

extern "C" void kernel_launch(void* const* d_in, const int* in_sizes, int n_in,
                              void* d_out, int out_size, void* d_ws, size_t ws_size,
                              hipStream_t stream) {
    const float* query = (const float*)d_in[0];
    const float* key   = (const float*)d_in[1];
    const float* Wq    = (const float*)d_in[2];
    const float* bq    = (const float*)d_in[3];
    const float* Wk    = (const float*)d_in[4];
    const float* bk    = (const float*)d_in[5];
    const float* v     = (const float*)d_in[6];
    float* out = (float*)d_out;

    char* ws = (char*)d_ws;
    float* wsNV = (float*)ws;                       // 512 B
    float* wsQ  = (float*)(ws + 4096);              // 256 KB (qb = q + bq + bk)
    short* wsB  = (short*)(ws + 524288);            // 1 MB swizzled bf16 Wk (lane-contiguous)
    float* wsP  = (float*)(ws + 2 * 1024 * 1024);   // 33.55 MB partial contexts

    size_t need = 2 * 1024 * 1024 + (size_t)GRID * (H_ * KD_) * sizeof(float);

    nv_kernel<<<1, 128, 0, stream>>>(v, wsNV);
    q_kernel<<<dim3(64, 4), 256, 0, stream>>>(query, Wq, bq, bk, wsQ);
    swz_kernel<<<256, 256, 0, stream>>>(Wk, wsB);

    if (ws_size >= need) {
        attn_kernel<false><<<GRID, 256, 0, stream>>>(key, wsB, wsQ, wsNV, wsP);
        reduce_kernel<<<256, 256, 0, stream>>>(wsP, out);
    } else {
        hipMemsetAsync(d_out, 0, (size_t)out_size * sizeof(float), stream);
        attn_kernel<true><<<GRID, 256, 0, stream>>>(key, wsB, wsQ, wsNV, out);
    }
}

// Round 6
// 502.190 us; speedup vs baseline: 1.2288x; 1.2288x over previous
//
#include <hip/hip_runtime.h>

// Problem constants (from reference): B=64, TQ=1, TK=2048, QD=KD=512, U=1024, H=8, D=128
#define B_   64
#define TK_  2048
#define KD_  512
#define U_   1024
#define H_   8
#define D_   128
#define MT   64              // t-rows per workgroup tile
#define APAD 8               // pad 8 bf16 (16B) -> 2-way LDS bank conflicts only (free)
#define ASTR (KD_ + APAD)    // 520 shorts per row
#define NTILE (TK_ / MT)     // 32 t-tiles per batch
#define GRID (B_ * NTILE)    // 2048 workgroups

typedef float f32x4 __attribute__((ext_vector_type(4)));
typedef short short8 __attribute__((ext_vector_type(8)));

__device__ __forceinline__ short f2bf(float f) {
    unsigned u = __float_as_uint(f);
    u += 0x7fffu + ((u >> 16) & 1u);          // round-to-nearest-even
    return (short)(u >> 16);
}
__device__ __forceinline__ float bf2f(short s) {
    return __uint_as_float(((unsigned)(unsigned short)s) << 16);
}
__device__ __forceinline__ float tanh_fast(float x) {
    // tanh(x) = 1 - 2/(1+exp(2x)); exact at +-inf saturation, ~1e-6 rel err
    float e = __builtin_amdgcn_exp2f(x * 2.885390081777927f);   // exp(2x)
    return 1.0f - 2.0f * __builtin_amdgcn_rcpf(1.0f + e);
}

// ---------------- setup kernel 1: normed_v = g * v * rsqrt(sum v^2) ----------------
__global__ void nv_kernel(const float* __restrict__ v, float* __restrict__ wsNV) {
    __shared__ float red[D_];
    int tid = threadIdx.x;
    float x = v[tid];
    red[tid] = x * x;
    __syncthreads();
    if (tid == 0) {
        float s = 0.f;
        for (int i = 0; i < D_; ++i) s += red[i];
        red[0] = rsqrtf(s) * 0.08838834764831845f;   // 1/sqrt(128)
    }
    __syncthreads();
    wsNV[tid] = x * red[0];
}

// ---------------- setup kernel 2: qb[b][u] = query[b,:].Wq[u,:] + bq[u] + bk[u] ----------------
__global__ void q_kernel(const float* __restrict__ query, const float* __restrict__ Wq,
                         const float* __restrict__ bq, const float* __restrict__ bk,
                         float* __restrict__ wsQ) {
    __shared__ float qrow[KD_];
    int b = blockIdx.x, ug = blockIdx.y, tid = threadIdx.x;
    if (tid < 128) ((float4*)qrow)[tid] = ((const float4*)(query + (size_t)b * KD_))[tid];
    __syncthreads();
    int u = ug * 256 + tid;
    const float4* wq = (const float4*)(Wq + (size_t)u * KD_);
    const float4* q4 = (const float4*)qrow;
    float acc = 0.f;
#pragma unroll 8
    for (int i = 0; i < KD_ / 4; ++i) {
        float4 a = q4[i], w = wq[i];
        acc += a.x * w.x + a.y * w.y + a.z * w.z + a.w * w.w;
    }
    wsQ[(size_t)b * U_ + u] = acc + bq[u] + bk[u];
}

// ---------------- setup kernel 3: swizzle Wk (fp32) into fragment-major bf16 ----------------
// ks-MAJOR slot order: oslot = ks*64 + ublk, lane-major within slot.
// COALESCING: for a fixed frag, a wave's 64 lanes read one contiguous 1KB block
// (16 cache lines/instruction). [R5 lesson: lane-contiguous layout = 128B lane
// stride = 64 lines/instruction = 4x VMEM cost -> MfmaUtil 27->17. Reverted.]
// within slot: lane l holds 8 bf16: u = ublk*16 + (l&15), k = ks*32 + (l>>4)*8 + j
__global__ void swz_kernel(const float* __restrict__ Wk, short* __restrict__ wsB) {
    int g = blockIdx.x * 256 + threadIdx.x;   // 0..65535 lane-frags
    int slot = g >> 6, l = g & 63;
    int ublk = slot >> 4, ks = slot & 15;
    int u = ublk * 16 + (l & 15);
    int k0 = ks * 32 + ((l >> 4) << 3);
    const float* src = Wk + (size_t)u * KD_ + k0;
    short8 o;
#pragma unroll
    for (int j = 0; j < 8; ++j) o[j] = f2bf(src[j]);
    int oslot = ks * 64 + ublk;               // ks-major
    *(short8*)(wsB + ((size_t)oslot * 64 + l) * 8) = o;
}

// ---------------- main fused kernel ----------------
// grid: 2048 = 64 b * 32 t-tiles; block 256 (4 waves); 2 WGs/CU (LDS ~70.7 KB)
// 2-deep in-chunk B prefetch (bbA/bbB). Register discipline (anti-spill):
//  - qv/nv loaded INSIDE the epilogue (L2-hit reloads), not held across the GEMM
//  - only bbA (32 regs) crosses SCORE_EPI (carrying chunk-1 ks=0)
// ATOMIC=false: write per-block partial ctx to `outp` (ws), reduced by reduce_kernel.
// ATOMIC=true : legacy fallback, atomicAdd into out (requires pre-zeroed out).

#define LOAD_A(a_, ksv)                                                               \
    _Pragma("unroll")                                                                 \
    for (int mf = 0; mf < 4; ++mf)                                                    \
        a_[mf] = *(const short8*)&As[(mf * 16 + l15) * ASTR + (ksv) * 32 + (lq << 3)];

#define MFMA32(a_, buf)                                                               \
    __builtin_amdgcn_s_setprio(1);                                                    \
    _Pragma("unroll")                                                                 \
    for (int mf = 0; mf < 4; ++mf)                                                    \
        _Pragma("unroll")                                                             \
        for (int nf = 0; nf < 8; ++nf)                                                \
            acc[mf][nf] = __builtin_amdgcn_mfma_f32_16x16x32_bf16(a_[mf], buf[nf],    \
                                                                  acc[mf][nf], 0, 0, 0); \
    __builtin_amdgcn_s_setprio(0);

#define PREF_B(buf, pidx)                                                             \
    _Pragma("unroll")                                                                 \
    for (int nf = 0; nf < 8; ++nf) buf[nf] = bp[(pidx) + nf * 64];

#define GSTEP(ksv, buf, pidx) { short8 a_[4]; LOAD_A(a_, ksv); MFMA32(a_, buf); PREF_B(buf, pidx); }
#define GSTEP_NP(ksv, buf)    { short8 a_[4]; LOAD_A(a_, ksv); MFMA32(a_, buf); }

#define ZERO_ACC                                                                      \
    _Pragma("unroll")                                                                 \
    for (int mf = 0; mf < 4; ++mf)                                                    \
        _Pragma("unroll")                                                             \
        for (int nf = 0; nf < 8; ++nf) acc[mf][nf] = (f32x4){0.f, 0.f, 0.f, 0.f};

// score epilogue: s[t][h] = sum_d nv[d] * tanh(k + qb)
// qv/nv loaded here (L2-hit, reused 16x each) instead of being live across the GEMM.
// C/D layout: row t = mf*16 + lq*4 + r, col d = nf*16 + l15
#define SCORE_EPI(ubv, hh)                                                            \
    {                                                                                 \
        float qv_[8], nv_[8];                                                         \
        _Pragma("unroll")                                                             \
        for (int nf = 0; nf < 8; ++nf) {                                              \
            int d = nf * 16 + l15;                                                    \
            qv_[nf] = wsQ[(size_t)b * U_ + (ubv) + d];                                \
            nv_[nf] = wsNV[d];                                                        \
        }                                                                             \
        _Pragma("unroll")                                                             \
        for (int mf = 0; mf < 4; ++mf)                                                \
            _Pragma("unroll")                                                         \
            for (int r = 0; r < 4; ++r) {                                             \
                float p = 0.f;                                                        \
                _Pragma("unroll")                                                     \
                for (int nf = 0; nf < 8; ++nf)                                        \
                    p += nv_[nf] * tanh_fast(acc[mf][nf][r] + qv_[nf]);               \
                p += __shfl_xor(p, 1);                                                \
                p += __shfl_xor(p, 2);                                                \
                p += __shfl_xor(p, 4);                                                \
                p += __shfl_xor(p, 8);                                                \
                if (l15 == 0) S[mf * 16 + lq * 4 + r][hh] = p;                        \
            }                                                                         \
    }

template <bool ATOMIC>
__global__ __launch_bounds__(256, 2) void attn_kernel(
    const float* __restrict__ key, const short* __restrict__ wsB,
    const float* __restrict__ wsQ, const float* __restrict__ wsNV,
    float* __restrict__ outp)
{
    __shared__ short As[MT * ASTR];   // bf16 key tile, reused for GEMM-A and value
    __shared__ float S[MT][H_];       // scores
    __shared__ float Wt[MT][H_];      // softmax weights

    int bx = blockIdx.x;
    int b = bx & 63, tt = bx >> 6;
    int tid = threadIdx.x;
    int w = tid >> 6, l = tid & 63;
    int l15 = l & 15, lq = l >> 4;
    const short8* bp = (const short8*)wsB;

    // each (wave, chunk) covers exactly one head: chunk0 -> h=w, chunk1 -> h=4+w
    int ub0 = w * 128, ub1 = 512 + w * 128;
    int bidx0 = (ub0 >> 4) * 64 + l;          // short8 base index, ks-major layout
    int bidx1 = (ub1 >> 4) * 64 + l;

    // ---- prefetch chunk-0 B-frags (ks=0,1) BEFORE the staging barrier ----
    // (global reads, no LDS dependency: latency hides under the stage phase)
    short8 bbA[8], bbB[8];
    PREF_B(bbA, bidx0);
    PREF_B(bbB, bidx0 + 4096);

    // ---- stage key tile [64 x 512] fp32 -> bf16 LDS (coalesced float4) ----
    const float4* src = (const float4*)(key + ((size_t)b * TK_ + (size_t)tt * MT) * KD_);
#pragma unroll 8
    for (int j = 0; j < 32; ++j) {
        int i = tid + j * 256;                 // 8192 float4 total
        float4 v = src[i];
        int t = i >> 7, c4 = (i & 127) << 2;
        short4 h4;
        h4.x = f2bf(v.x); h4.y = f2bf(v.y); h4.z = f2bf(v.z); h4.w = f2bf(v.w);
        *(short4*)&As[t * ASTR + c4] = h4;
    }
    __syncthreads();

    f32x4 acc[4][8];

    // ---- chunk 0 GEMM: 2-deep software-pipelined B prefetch ----
    ZERO_ACC;
#pragma unroll 1
    for (int ks = 0; ks < 14; ks += 2) {
        GSTEP(ks,     bbA, bidx0 + (ks + 2) * 4096);
        GSTEP(ks + 1, bbB, bidx0 + (ks + 3) * 4096);
    }
    // tail: after ks=14 consumes bbA, refill bbA with chunk-1 ks=0 (only 32 regs
    // cross the epilogue); bbB is consumed by ks=15 and left dead over the epilogue.
    GSTEP(14, bbA, bidx1);
    GSTEP_NP(15, bbB);
    SCORE_EPI(ub0, w);                         // bbA (chunk-1 ks0) in flight under this

    // ---- low-pressure window: chunk-1 ks=1 prefetch ----
    PREF_B(bbB, bidx1 + 4096);

    // ---- chunk 1 GEMM ----
    ZERO_ACC;
#pragma unroll 1
    for (int ks = 0; ks < 14; ks += 2) {
        GSTEP(ks,     bbA, bidx1 + (ks + 2) * 4096);
        GSTEP(ks + 1, bbB, bidx1 + (ks + 3) * 4096);
    }
    GSTEP_NP(14, bbA);
    GSTEP_NP(15, bbB);
    SCORE_EPI(ub1, 4 + w);
    __syncthreads();

    // ---- softmax over HEADS per t (legacy F.softmax dim=1) ----
    if (tid < MT) {
        f32x4 s0 = *(const f32x4*)&S[tid][0];
        f32x4 s1 = *(const f32x4*)&S[tid][4];
        float mx = fmaxf(fmaxf(fmaxf(s0[0], s0[1]), fmaxf(s0[2], s0[3])),
                         fmaxf(fmaxf(s1[0], s1[1]), fmaxf(s1[2], s1[3])));
        f32x4 e0, e1;
        float sum = 0.f;
#pragma unroll
        for (int h = 0; h < 4; ++h) {
            e0[h] = __builtin_amdgcn_exp2f((s0[h] - mx) * 1.4426950408889634f);
            sum += e0[h];
        }
#pragma unroll
        for (int h = 0; h < 4; ++h) {
            e1[h] = __builtin_amdgcn_exp2f((s1[h] - mx) * 1.4426950408889634f);
            sum += e1[h];
        }
        float inv = __builtin_amdgcn_rcpf(sum);
#pragma unroll
        for (int h = 0; h < 4; ++h) { e0[h] *= inv; e1[h] *= inv; }
        *(f32x4*)&Wt[tid][0] = e0;
        *(f32x4*)&Wt[tid][4] = e1;
    }
    __syncthreads();

    // ---- partial context: ctx[h][d] = sum_t w[t][h] * key[t][d] ----
    int dg = (tid & 127) << 2;        // d group of 4
    int hb = (tid >> 7) << 2;         // h base: 0 or 4
    float cacc[4][4] = {};
#pragma unroll 4
    for (int t = 0; t < MT; ++t) {
        short4 kk = *(const short4*)&As[t * ASTR + dg];
        f32x4 wt4 = *(const f32x4*)&Wt[t][hb];   // one b128 broadcast read
        float k0 = bf2f(kk.x), k1 = bf2f(kk.y), k2 = bf2f(kk.z), k3 = bf2f(kk.w);
#pragma unroll
        for (int j = 0; j < 4; ++j) {
            cacc[j][0] += wt4[j] * k0; cacc[j][1] += wt4[j] * k1;
            cacc[j][2] += wt4[j] * k2; cacc[j][3] += wt4[j] * k3;
        }
    }
    if (ATOMIC) {
        float* ob = outp + (size_t)b * (H_ * KD_);
#pragma unroll
        for (int j = 0; j < 4; ++j)
#pragma unroll
            for (int d = 0; d < 4; ++d)
                atomicAdd(&ob[(hb + j) * KD_ + dg + d], cacc[j][d]);
    } else {
        // fully coalesced float4 stores: block-private partial [8][512]
        float* pb = outp + (size_t)bx * (H_ * KD_);
#pragma unroll
        for (int j = 0; j < 4; ++j)
            *(f32x4*)&pb[(hb + j) * KD_ + dg] = *(f32x4*)&cacc[j][0];
    }
}

// ---------------- reduce kernel: out[b][u] = sum_tt partial[tt*64+b][u] ----------------
__global__ void reduce_kernel(const float* __restrict__ partial, float* __restrict__ out) {
    int o = blockIdx.x * 256 + threadIdx.x;   // float4 index, 65536 total
    int b = o >> 10;                          // 1024 float4 per batch
    int u4 = o & 1023;
    const f32x4* p4 = (const f32x4*)partial;
    f32x4 s = {0.f, 0.f, 0.f, 0.f};
#pragma unroll 8
    for (int tt = 0; tt < NTILE; ++tt)
        s += p4[((size_t)(tt * 64 + b)) * 1024 + u4];
    ((f32x4*)out)[o] = s;
}

extern "C" void kernel_launch(void* const* d_in, const int* in_sizes, int n_in,
                              void* d_out, int out_size, void* d_ws, size_t ws_size,
                              hipStream_t stream) {
    const float* query = (const float*)d_in[0];
    const float* key   = (const float*)d_in[1];
    const float* Wq    = (const float*)d_in[2];
    const float* bq    = (const float*)d_in[3];
    const float* Wk    = (const float*)d_in[4];
    const float* bk    = (const float*)d_in[5];
    const float* v     = (const float*)d_in[6];
    float* out = (float*)d_out;

    char* ws = (char*)d_ws;
    float* wsNV = (float*)ws;                       // 512 B
    float* wsQ  = (float*)(ws + 4096);              // 256 KB (qb = q + bq + bk)
    short* wsB  = (short*)(ws + 524288);            // 1 MB swizzled bf16 Wk (ks-major)
    float* wsP  = (float*)(ws + 2 * 1024 * 1024);   // 33.55 MB partial contexts

    size_t need = 2 * 1024 * 1024 + (size_t)GRID * (H_ * KD_) * sizeof(float);

    nv_kernel<<<1, 128, 0, stream>>>(v, wsNV);
    q_kernel<<<dim3(64, 4), 256, 0, stream>>>(query, Wq, bq, bk, wsQ);
    swz_kernel<<<256, 256, 0, stream>>>(Wk, wsB);

    if (ws_size >= need) {
        attn_kernel<false><<<GRID, 256, 0, stream>>>(key, wsB, wsQ, wsNV, wsP);
        reduce_kernel<<<256, 256, 0, stream>>>(wsP, out);
    } else {
        hipMemsetAsync(d_out, 0, (size_t)out_size * sizeof(float), stream);
        attn_kernel<true><<<GRID, 256, 0, stream>>>(key, wsB, wsQ, wsNV, out);
    }
}

// Round 8
// 498.936 us; speedup vs baseline: 1.2368x; 1.0065x over previous
//
#include <hip/hip_runtime.h>

// Problem constants (from reference): B=64, TQ=1, TK=2048, QD=KD=512, U=1024, H=8, D=128
#define B_   64
#define TK_  2048
#define KD_  512
#define U_   1024
#define H_   8
#define D_   128
#define MT   64              // t-rows per workgroup tile
#define APAD 8               // pad 8 bf16 (16B) -> 2-way LDS bank conflicts only (free)
#define ASTR (KD_ + APAD)    // 520 shorts per row
#define NTILE (TK_ / MT)     // 32 t-tiles per batch
#define GRID (B_ * NTILE)    // 2048 workgroups

typedef float f32x4 __attribute__((ext_vector_type(4)));
typedef short short8 __attribute__((ext_vector_type(8)));

__device__ __forceinline__ short f2bf(float f) {
    unsigned u = __float_as_uint(f);
    u += 0x7fffu + ((u >> 16) & 1u);          // round-to-nearest-even
    return (short)(u >> 16);
}
__device__ __forceinline__ float bf2f(short s) {
    return __uint_as_float(((unsigned)(unsigned short)s) << 16);
}
__device__ __forceinline__ float tanh_fast(float x) {
    // tanh(x) = 1 - 2/(1+exp(2x)); exact at +-inf saturation, ~1e-6 rel err
    float e = __builtin_amdgcn_exp2f(x * 2.885390081777927f);   // exp(2x)
    return 1.0f - 2.0f * __builtin_amdgcn_rcpf(1.0f + e);
}

// ---------------- fused setup kernel ----------------
// The three setup stages are mutually independent (each reads only d_in, writes
// disjoint ws regions), so they run as one launch partitioned by blockIdx.x:
//   bx == 0      : normed_v = g * v * rsqrt(sum v^2)            -> wsNV
//   bx in [1,257): qb[b][u] = query[b,:].Wq[u,:] + bq[u] + bk[u] -> wsQ
//   bx >= 257    : swizzle Wk (fp32) -> fragment-major bf16      -> wsB
// swz layout: ks-MAJOR slot order oslot = ks*64 + ublk, lane-major within slot.
// COALESCING invariant: a GEMM frag load = 64 lanes x 16B = ONE contiguous 1KB
// block (16 cache lines/instruction). [R5 lesson: lane-contiguous layout = 128B
// lane stride = 4x VMEM cost -> MfmaUtil 27->17. Never break this.]
// within slot: lane l holds 8 bf16: u = ublk*16 + (l&15), k = ks*32 + (l>>4)*8 + j
__global__ void setup_kernel(const float* __restrict__ v, const float* __restrict__ query,
                             const float* __restrict__ Wq, const float* __restrict__ bq,
                             const float* __restrict__ bk, const float* __restrict__ Wk,
                             float* __restrict__ wsNV, float* __restrict__ wsQ,
                             short* __restrict__ wsB) {
    int bx = blockIdx.x, tid = threadIdx.x;
    if (bx == 0) {
        // ---- nv: normed_v ----
        __shared__ float red[D_];
        float x = 0.f;
        if (tid < D_) { x = v[tid]; red[tid] = x * x; }
        __syncthreads();
        if (tid == 0) {
            float s = 0.f;
            for (int i = 0; i < D_; ++i) s += red[i];
            red[0] = rsqrtf(s) * 0.08838834764831845f;   // 1/sqrt(128)
        }
        __syncthreads();
        if (tid < D_) wsNV[tid] = x * red[0];
    } else if (bx < 257) {
        // ---- q: qb = q.Wq + bq + bk ----
        __shared__ float qrow[KD_];
        int idx = bx - 1;
        int b = idx >> 2, ug = idx & 3;
        if (tid < 128) ((float4*)qrow)[tid] = ((const float4*)(query + (size_t)b * KD_))[tid];
        __syncthreads();
        int u = ug * 256 + tid;
        const float4* wq = (const float4*)(Wq + (size_t)u * KD_);
        const float4* q4 = (const float4*)qrow;
        float acc = 0.f;
#pragma unroll 8
        for (int i = 0; i < KD_ / 4; ++i) {
            float4 a = q4[i], w = wq[i];
            acc += a.x * w.x + a.y * w.y + a.z * w.z + a.w * w.w;
        }
        wsQ[(size_t)b * U_ + u] = acc + bq[u] + bk[u];
    } else {
        // ---- swz: Wk -> bf16 fragment-major ----
        int g = (bx - 257) * 256 + tid;       // 0..65535 lane-frags
        int slot = g >> 6, l = g & 63;
        int ublk = slot >> 4, ks = slot & 15;
        int u = ublk * 16 + (l & 15);
        int k0 = ks * 32 + ((l >> 4) << 3);
        const float* src = Wk + (size_t)u * KD_ + k0;
        short8 o;
#pragma unroll
        for (int j = 0; j < 8; ++j) o[j] = f2bf(src[j]);
        int oslot = ks * 64 + ublk;           // ks-major
        *(short8*)(wsB + ((size_t)oslot * 64 + l) * 8) = o;
    }
}

// ---------------- main fused kernel ----------------
// grid: 2048 = 64 b * 32 t-tiles; block 256 (4 waves); 2 WGs/CU (LDS ~70.7 KB)
// 2-deep in-chunk B prefetch (bbA/bbB). Register discipline (anti-spill):
//  - qv/nv loaded INSIDE the epilogue (L2-hit reloads), not held across the GEMM
//  - only bbA (32 regs) crosses SCORE_EPI (carrying chunk-1 ks=0)
// ATOMIC=false: write per-block partial ctx to `outp` (ws), reduced by reduce_kernel.
// ATOMIC=true : legacy fallback, atomicAdd into out (requires pre-zeroed out).

#define LOAD_A(a_, ksv)                                                               \
    _Pragma("unroll")                                                                 \
    for (int mf = 0; mf < 4; ++mf)                                                    \
        a_[mf] = *(const short8*)&As[(mf * 16 + l15) * ASTR + (ksv) * 32 + (lq << 3)];

#define MFMA32(a_, buf)                                                               \
    __builtin_amdgcn_s_setprio(1);                                                    \
    _Pragma("unroll")                                                                 \
    for (int mf = 0; mf < 4; ++mf)                                                    \
        _Pragma("unroll")                                                             \
        for (int nf = 0; nf < 8; ++nf)                                                \
            acc[mf][nf] = __builtin_amdgcn_mfma_f32_16x16x32_bf16(a_[mf], buf[nf],    \
                                                                  acc[mf][nf], 0, 0, 0); \
    __builtin_amdgcn_s_setprio(0);

#define PREF_B(buf, pidx)                                                             \
    _Pragma("unroll")                                                                 \
    for (int nf = 0; nf < 8; ++nf) buf[nf] = bp[(pidx) + nf * 64];

#define GSTEP(ksv, buf, pidx) { short8 a_[4]; LOAD_A(a_, ksv); MFMA32(a_, buf); PREF_B(buf, pidx); }
#define GSTEP_NP(ksv, buf)    { short8 a_[4]; LOAD_A(a_, ksv); MFMA32(a_, buf); }

#define ZERO_ACC                                                                      \
    _Pragma("unroll")                                                                 \
    for (int mf = 0; mf < 4; ++mf)                                                    \
        _Pragma("unroll")                                                             \
        for (int nf = 0; nf < 8; ++nf) acc[mf][nf] = (f32x4){0.f, 0.f, 0.f, 0.f};

// score epilogue: s[t][h] = sum_d nv[d] * tanh(k + qb)
// qv/nv loaded here (L2-hit, reused 16x each) instead of being live across the GEMM.
// C/D layout: row t = mf*16 + lq*4 + r, col d = nf*16 + l15
#define SCORE_EPI(ubv, hh)                                                            \
    {                                                                                 \
        float qv_[8], nv_[8];                                                         \
        _Pragma("unroll")                                                             \
        for (int nf = 0; nf < 8; ++nf) {                                              \
            int d = nf * 16 + l15;                                                    \
            qv_[nf] = wsQ[(size_t)b * U_ + (ubv) + d];                                \
            nv_[nf] = wsNV[d];                                                        \
        }                                                                             \
        _Pragma("unroll")                                                             \
        for (int mf = 0; mf < 4; ++mf)                                                \
            _Pragma("unroll")                                                         \
            for (int r = 0; r < 4; ++r) {                                             \
                float p = 0.f;                                                        \
                _Pragma("unroll")                                                     \
                for (int nf = 0; nf < 8; ++nf)                                        \
                    p += nv_[nf] * tanh_fast(acc[mf][nf][r] + qv_[nf]);               \
                p += __shfl_xor(p, 1);                                                \
                p += __shfl_xor(p, 2);                                                \
                p += __shfl_xor(p, 4);                                                \
                p += __shfl_xor(p, 8);                                                \
                if (l15 == 0) S[mf * 16 + lq * 4 + r][hh] = p;                        \
            }                                                                         \
    }

template <bool ATOMIC>
__global__ __launch_bounds__(256, 2) void attn_kernel(
    const float* __restrict__ key, const short* __restrict__ wsB,
    const float* __restrict__ wsQ, const float* __restrict__ wsNV,
    float* __restrict__ outp)
{
    __shared__ short As[MT * ASTR];   // bf16 key tile, reused for GEMM-A and value
    __shared__ float S[MT][H_];       // scores
    __shared__ float Wt[MT][H_];      // softmax weights

    int bx = blockIdx.x;
    int b = bx & 63, tt = bx >> 6;
    int tid = threadIdx.x;
    int w = tid >> 6, l = tid & 63;
    int l15 = l & 15, lq = l >> 4;
    const short8* bp = (const short8*)wsB;

    // each (wave, chunk) covers exactly one head: chunk0 -> h=w, chunk1 -> h=4+w
    int ub0 = w * 128, ub1 = 512 + w * 128;
    int bidx0 = (ub0 >> 4) * 64 + l;          // short8 base index, ks-major layout
    int bidx1 = (ub1 >> 4) * 64 + l;

    // ---- prefetch chunk-0 B-frags (ks=0,1) BEFORE the staging barrier ----
    // (global reads, no LDS dependency: latency hides under the stage phase)
    short8 bbA[8], bbB[8];
    PREF_B(bbA, bidx0);
    PREF_B(bbB, bidx0 + 4096);

    // ---- stage key tile [64 x 512] fp32 -> bf16 LDS (coalesced float4) ----
    const float4* src = (const float4*)(key + ((size_t)b * TK_ + (size_t)tt * MT) * KD_);
#pragma unroll 8
    for (int j = 0; j < 32; ++j) {
        int i = tid + j * 256;                 // 8192 float4 total
        float4 v = src[i];
        int t = i >> 7, c4 = (i & 127) << 2;
        short4 h4;
        h4.x = f2bf(v.x); h4.y = f2bf(v.y); h4.z = f2bf(v.z); h4.w = f2bf(v.w);
        *(short4*)&As[t * ASTR + c4] = h4;
    }
    __syncthreads();

    f32x4 acc[4][8];

    // ---- chunk 0 GEMM: 2-deep software-pipelined B prefetch ----
    ZERO_ACC;
#pragma unroll 1
    for (int ks = 0; ks < 14; ks += 2) {
        GSTEP(ks,     bbA, bidx0 + (ks + 2) * 4096);
        GSTEP(ks + 1, bbB, bidx0 + (ks + 3) * 4096);
    }
    // tail: after ks=14 consumes bbA, refill bbA with chunk-1 ks=0 (only 32 regs
    // cross the epilogue); bbB is consumed by ks=15 and left dead over the epilogue.
    GSTEP(14, bbA, bidx1);
    GSTEP_NP(15, bbB);
    SCORE_EPI(ub0, w);                         // bbA (chunk-1 ks0) in flight under this

    // ---- low-pressure window: chunk-1 ks=1 prefetch ----
    PREF_B(bbB, bidx1 + 4096);

    // ---- chunk 1 GEMM ----
    ZERO_ACC;
#pragma unroll 1
    for (int ks = 0; ks < 14; ks += 2) {
        GSTEP(ks,     bbA, bidx1 + (ks + 2) * 4096);
        GSTEP(ks + 1, bbB, bidx1 + (ks + 3) * 4096);
    }
    GSTEP_NP(14, bbA);
    GSTEP_NP(15, bbB);
    SCORE_EPI(ub1, 4 + w);
    __syncthreads();

    // ---- softmax over HEADS per t (legacy F.softmax dim=1) ----
    if (tid < MT) {
        f32x4 s0 = *(const f32x4*)&S[tid][0];
        f32x4 s1 = *(const f32x4*)&S[tid][4];
        float mx = fmaxf(fmaxf(fmaxf(s0[0], s0[1]), fmaxf(s0[2], s0[3])),
                         fmaxf(fmaxf(s1[0], s1[1]), fmaxf(s1[2], s1[3])));
        f32x4 e0, e1;
        float sum = 0.f;
#pragma unroll
        for (int h = 0; h < 4; ++h) {
            e0[h] = __builtin_amdgcn_exp2f((s0[h] - mx) * 1.4426950408889634f);
            sum += e0[h];
        }
#pragma unroll
        for (int h = 0; h < 4; ++h) {
            e1[h] = __builtin_amdgcn_exp2f((s1[h] - mx) * 1.4426950408889634f);
            sum += e1[h];
        }
        float inv = __builtin_amdgcn_rcpf(sum);
#pragma unroll
        for (int h = 0; h < 4; ++h) { e0[h] *= inv; e1[h] *= inv; }
        *(f32x4*)&Wt[tid][0] = e0;
        *(f32x4*)&Wt[tid][4] = e1;
    }
    __syncthreads();

    // ---- partial context: ctx[h][d] = sum_t w[t][h] * key[t][d] ----
    int dg = (tid & 127) << 2;        // d group of 4
    int hb = (tid >> 7) << 2;         // h base: 0 or 4
    float cacc[4][4] = {};
#pragma unroll 4
    for (int t = 0; t < MT; ++t) {
        short4 kk = *(const short4*)&As[t * ASTR + dg];
        f32x4 wt4 = *(const f32x4*)&Wt[t][hb];   // one b128 broadcast read
        float k0 = bf2f(kk.x), k1 = bf2f(kk.y), k2 = bf2f(kk.z), k3 = bf2f(kk.w);
#pragma unroll
        for (int j = 0; j < 4; ++j) {
            cacc[j][0] += wt4[j] * k0; cacc[j][1] += wt4[j] * k1;
            cacc[j][2] += wt4[j] * k2; cacc[j][3] += wt4[j] * k3;
        }
    }
    if (ATOMIC) {
        float* ob = outp + (size_t)b * (H_ * KD_);
#pragma unroll
        for (int j = 0; j < 4; ++j)
#pragma unroll
            for (int d = 0; d < 4; ++d)
                atomicAdd(&ob[(hb + j) * KD_ + dg + d], cacc[j][d]);
    } else {
        // fully coalesced float4 stores: block-private partial [8][512]
        float* pb = outp + (size_t)bx * (H_ * KD_);
#pragma unroll
        for (int j = 0; j < 4; ++j)
            *(f32x4*)&pb[(hb + j) * KD_ + dg] = *(f32x4*)&cacc[j][0];
    }
}

// ---------------- reduce kernel: out[b][u] = sum_tt partial[tt*64+b][u] ----------------
__global__ void reduce_kernel(const float* __restrict__ partial, float* __restrict__ out) {
    int o = blockIdx.x * 256 + threadIdx.x;   // float4 index, 65536 total
    int b = o >> 10;                          // 1024 float4 per batch
    int u4 = o & 1023;
    const f32x4* p4 = (const f32x4*)partial;
    f32x4 s = {0.f, 0.f, 0.f, 0.f};
#pragma unroll 8
    for (int tt = 0; tt < NTILE; ++tt)
        s += p4[((size_t)(tt * 64 + b)) * 1024 + u4];
    ((f32x4*)out)[o] = s;
}

extern "C" void kernel_launch(void* const* d_in, const int* in_sizes, int n_in,
                              void* d_out, int out_size, void* d_ws, size_t ws_size,
                              hipStream_t stream) {
    const float* query = (const float*)d_in[0];
    const float* key   = (const float*)d_in[1];
    const float* Wq    = (const float*)d_in[2];
    const float* bq    = (const float*)d_in[3];
    const float* Wk    = (const float*)d_in[4];
    const float* bk    = (const float*)d_in[5];
    const float* v     = (const float*)d_in[6];
    float* out = (float*)d_out;

    char* ws = (char*)d_ws;
    float* wsNV = (float*)ws;                       // 512 B
    float* wsQ  = (float*)(ws + 4096);              // 256 KB (qb = q + bq + bk)
    short* wsB  = (short*)(ws + 524288);            // 1 MB swizzled bf16 Wk (ks-major)
    float* wsP  = (float*)(ws + 2 * 1024 * 1024);   // 33.55 MB partial contexts

    size_t need = 2 * 1024 * 1024 + (size_t)GRID * (H_ * KD_) * sizeof(float);

    setup_kernel<<<513, 256, 0, stream>>>(v, query, Wq, bq, bk, Wk, wsNV, wsQ, wsB);

    if (ws_size >= need) {
        attn_kernel<false><<<GRID, 256, 0, stream>>>(key, wsB, wsQ, wsNV, wsP);
        reduce_kernel<<<256, 256, 0, stream>>>(wsP, out);
    } else {
        hipMemsetAsync(d_out, 0, (size_t)out_size * sizeof(float), stream);
        attn_kernel<true><<<GRID, 256, 0, stream>>>(key, wsB, wsQ, wsNV, out);
    }
}